// Round 5
// baseline (1153.031 us; speedup 1.0000x reference)
//
#include <hip/hip_runtime.h>
#include <math.h>

#define Lh 2304
#define Ch 768
#define NHh 12
#define Bh 2
#define QS 4608   // row stride of fused qkv activation buffer (global q|k|v, local q|k|v)

typedef unsigned short ushort_t;
typedef unsigned int uint_t;
typedef __attribute__((ext_vector_type(8))) short bf16x8;
typedef __attribute__((ext_vector_type(4))) float f32x4;
#define MFMA16(a, b, c) __builtin_amdgcn_mfma_f32_16x16x32_bf16(a, b, c, 0, 0, 0)

__device__ __forceinline__ ushort_t f2bf(float f) {
    union { float f; uint_t u; } v; v.f = f;
    uint_t u = v.u + 0x7fffu + ((v.u >> 16) & 1u);   // RNE
    return (ushort_t)(u >> 16);
}

// ---------------------------------------------------------------- layernorm (fp32 in, bf16 out)
__global__ __launch_bounds__(256)
void layernorm_bf16_kernel(const float* __restrict__ x, const float* __restrict__ w,
                           const float* __restrict__ b, ushort_t* __restrict__ y)
{
    int row = blockIdx.x;
    int tid = threadIdx.x;
    const float* xr = x + (size_t)row * Ch;
    float v0 = xr[tid], v1 = xr[tid + 256], v2 = xr[tid + 512];
    __shared__ float red[256];
    red[tid] = v0 + v1 + v2;
    __syncthreads();
    for (int st = 128; st > 0; st >>= 1) {
        if (tid < st) red[tid] += red[tid + st];
        __syncthreads();
    }
    float mean = red[0] * (1.0f / 768.0f);
    __syncthreads();
    float d0 = v0 - mean, d1 = v1 - mean, d2 = v2 - mean;
    red[tid] = d0 * d0 + d1 * d1 + d2 * d2;
    __syncthreads();
    for (int st = 128; st > 0; st >>= 1) {
        if (tid < st) red[tid] += red[tid + st];
        __syncthreads();
    }
    float rstd = rsqrtf(red[0] * (1.0f / 768.0f) + 1e-6f);
    ushort_t* yr = y + (size_t)row * Ch;
    yr[tid]       = f2bf(d0 * rstd * w[tid]       + b[tid]);
    yr[tid + 256] = f2bf(d1 * rstd * w[tid + 256] + b[tid + 256]);
    yr[tid + 512] = f2bf(d2 * rstd * w[tid + 512] + b[tid + 512]);
}

// ---------------------------------------------------------------- mask pooling
__global__ __launch_bounds__(256)
void mask_pool_kernel(const float* __restrict__ mask, float* __restrict__ fg)
{
    int idx = blockIdx.x * 256 + threadIdx.x;
    if (idx >= Bh * 48 * 48) return;
    int b = idx / (48 * 48);
    int rem = idx % (48 * 48);
    int i = rem / 48, j = rem % 48;
    const float* mb = mask + (size_t)b * 192 * 192;
    float s = 0.0f;
    #pragma unroll
    for (int di = 0; di < 4; ++di)
        #pragma unroll
        for (int dj = 0; dj < 4; ++dj)
            s += mb[(i * 4 + di) * 192 + (j * 4 + dj)];
    fg[idx] = (s * (1.0f / 16.0f) > 0.4f) ? 1.0f : 0.0f;
}

__global__ __launch_bounds__(256)
void mask_win_kernel(const float* __restrict__ fg, float* __restrict__ bgw)
{
    int idx = blockIdx.x * 256 + threadIdx.x;
    if (idx >= Bh * 36) return;
    int b = idx / 36, rem = idx % 36;
    int wi = rem / 6, wj = rem % 6;
    float anybg = 0.0f;
    for (int r = 0; r < 8; ++r)
        for (int c = 0; c < 8; ++c) {
            int n = (wi * 8 + r) * 48 + wj * 8 + c;
            if (fg[b * Lh + n] == 0.0f) anybg = 1.0f;
        }
    bgw[idx] = anybg;
}

// ---------------------------------------------------------------- weight cast+transpose: W[K][N] f32 -> Wt[N][K] bf16
__global__ __launch_bounds__(256)
void transpose_cast_kernel(const float* __restrict__ W, ushort_t* __restrict__ Wt,
                           int K, int N)
{
    int n0 = blockIdx.x * 64;
    int k0 = blockIdx.y * 64;
    int tid = threadIdx.x;
    __shared__ float T[64][65];
    #pragma unroll
    for (int i = 0; i < 16; ++i) {
        int lin = i * 256 + tid;
        int r = lin >> 6, c = lin & 63;
        T[r][c] = W[(size_t)(k0 + r) * N + n0 + c];
    }
    __syncthreads();
    #pragma unroll
    for (int i = 0; i < 16; ++i) {
        int lin = i * 256 + tid;
        int r = lin >> 6, c = lin & 63;
        Wt[(size_t)(n0 + r) * K + k0 + c] = f2bf(T[c][r]);
    }
}

// ---------------------------------------------------------------- bf16 MFMA GEMM (BM=128, BN template)
// C[M,N] = act(A[M,K] @ Bt[N,K]^T + bias) [+residual] with optional row-masking.
// flags: 1=gelu, 2=bf16 out, 4=fg-masked add (C=res+fg[row]*v), 8=bg-local masked add
template<int BNt>
__global__ __launch_bounds__(256)
void gemm_bf16_t(const ushort_t* __restrict__ A, const ushort_t* __restrict__ Bt,
                 const float* __restrict__ bias, const float* __restrict__ residual,
                 void* __restrict__ C, int M, int N, int K, int flags,
                 const float* __restrict__ fg, const float* __restrict__ bgw)
{
    __shared__ ushort_t As[128][40];
    __shared__ ushort_t Bs[BNt][40];
    int bm = blockIdx.y * 128;
    int bn = blockIdx.x * BNt;
    int tid = threadIdx.x;
    int lane = tid & 63;
    int wave = tid >> 6;
    int wm = wave >> 1, wn = wave & 1;
    int quad = lane >> 4, l15 = lane & 15;
    constexpr int NJ = BNt / 32;     // frag cols per wave: 4 (BN=128) or 2 (BN=64)

    f32x4 acc[4][NJ];
    #pragma unroll
    for (int i = 0; i < 4; ++i)
        #pragma unroll
        for (int j = 0; j < NJ; ++j)
            acc[i][j] = (f32x4){0.f, 0.f, 0.f, 0.f};

    for (int k0 = 0; k0 < K; k0 += 32) {
        #pragma unroll
        for (int it = 0; it < 2; ++it) {
            int e = tid + it * 256;
            int row = e >> 2, g = e & 3;
            *(uint4*)&As[row][g * 8] = *(const uint4*)(A + (size_t)(bm + row) * K + k0 + g * 8);
        }
        #pragma unroll
        for (int it = 0; it < BNt / 64; ++it) {
            int e = tid + it * 256;
            int row = e >> 2, g = e & 3;
            *(uint4*)&Bs[row][g * 8] = *(const uint4*)(Bt + (size_t)(bn + row) * K + k0 + g * 8);
        }
        __syncthreads();
        bf16x8 af[4], bfr[NJ];
        #pragma unroll
        for (int i = 0; i < 4; ++i)
            af[i] = *(const bf16x8*)&As[wm * 64 + i * 16 + l15][quad * 8];
        #pragma unroll
        for (int j = 0; j < NJ; ++j)
            bfr[j] = *(const bf16x8*)&Bs[wn * (BNt / 2) + j * 16 + l15][quad * 8];
        #pragma unroll
        for (int i = 0; i < 4; ++i)
            #pragma unroll
            for (int j = 0; j < NJ; ++j)
                acc[i][j] = MFMA16(af[i], bfr[j], acc[i][j]);
        __syncthreads();
    }

    float bia[NJ];
    #pragma unroll
    for (int j = 0; j < NJ; ++j) bia[j] = bias[bn + wn * (BNt / 2) + j * 16 + l15];

    #pragma unroll
    for (int i = 0; i < 4; ++i) {
        #pragma unroll
        for (int r = 0; r < 4; ++r) {
            int row = bm + wm * 64 + i * 16 + quad * 4 + r;
            float keep = 1.0f;
            if (flags & 4) keep = (fg[row] != 0.0f) ? 1.0f : 0.0f;
            if (flags & 8) {
                int bb = (row >= Lh) ? 1 : 0;
                int n = row - bb * Lh;
                int ii = n / 48, jj = n % 48;
                keep = (fg[row] == 0.0f && bgw[bb * 36 + (ii >> 3) * 6 + (jj >> 3)] != 0.0f)
                           ? 1.0f : 0.0f;
            }
            #pragma unroll
            for (int j = 0; j < NJ; ++j) {
                int col = bn + wn * (BNt / 2) + j * 16 + l15;
                float v = acc[i][j][r] + bia[j];
                if (flags & 1) v = v * 0.5f * (1.0f + erff(v * 0.70710678f));
                float o;
                if (flags & (4 | 8)) o = residual[(size_t)row * N + col] + keep * v;
                else if (residual)   o = residual[(size_t)row * N + col] + v;
                else                 o = v;
                if (flags & 2) ((ushort_t*)C)[(size_t)row * N + col] = f2bf(o);
                else           ((float*)C)[(size_t)row * N + col] = o;
            }
        }
    }
}

// ---------------------------------------------------------------- MFMA flash attention (no-max softmax)
// QKV fused buffer [tok][4608]; qoff selects branch (0=global, 2304=local).
// mode 0: 128-q tile, 36 key tiles, fg mask, grid (18,NH,B). Wave w owns q rows
//         [w*32, w*32+32) as 2 stripes of 16; Q frags live in registers.
// mode 1: 64-q window tile, 1 key tile, grid (36,NH,B), wave owns 16 q rows.
// Vt XOR-swizzled: Vt[d][tok ^ ((d>>3)<<3)] -> conflict-free transposed staging.
__global__ __launch_bounds__(256)
void attn_mfma_kernel(const ushort_t* __restrict__ QKV, const float* __restrict__ fg,
                      ushort_t* __restrict__ O, int mode, int qoff)
{
    int tile = blockIdx.x;
    int h = blockIdx.y;
    int b = blockIdx.z;
    int tid = threadIdx.x;
    int lane = tid & 63;
    int wave = tid >> 6;
    int quad = lane >> 4, l15 = lane & 15;
    int wi = tile / 6, wj = tile % 6;    // local-mode window coords
    int nstripe = mode ? 1 : 2;

    __shared__ ushort_t Ks[64][72];
    __shared__ ushort_t Vt[64][72];
    __shared__ ushort_t Ps[128][72];
    __shared__ float fgs[64];

    // Q fragments from global into registers (loop-invariant)
    bf16x8 aq[2][2];
    for (int s = 0; s < nstripe; ++s) {
        int ql = mode ? (wave * 16 + l15) : (wave * 32 + s * 16 + l15);
        int tok = mode ? ((wi * 8 + (ql >> 3)) * 48 + wj * 8 + (ql & 7)) : tile * 128 + ql;
        const ushort_t* qbase = QKV + (size_t)(b * Lh + tok) * QS + qoff + h * 64;
        #pragma unroll
        for (int step = 0; step < 2; ++step)
            aq[s][step] = *(const bf16x8*)(qbase + step * 32 + quad * 8);
    }

    float l_part[2][4] = {{0.f}};
    f32x4 o_acc[2][4];
    #pragma unroll
    for (int s = 0; s < 2; ++s)
        #pragma unroll
        for (int t4 = 0; t4 < 4; ++t4) o_acc[s][t4] = (f32x4){0.f, 0.f, 0.f, 0.f};

    int nkt = mode ? 1 : 36;

    // prefetch tile 0 K/V
    uint4 kx[2], vx[2];
    #pragma unroll
    for (int it = 0; it < 2; ++it) {
        int e = tid + it * 256;
        int row = e >> 3, g = e & 7;
        int tok = mode ? ((wi * 8 + (row >> 3)) * 48 + wj * 8 + (row & 7)) : row;
        const ushort_t* base = QKV + (size_t)(b * Lh + tok) * QS + qoff + h * 64 + g * 8;
        kx[it] = *(const uint4*)(base + 768);
        vx[it] = *(const uint4*)(base + 1536);
    }
    float fgn = 0.f;
    if (!mode && tid < 64) fgn = fg[b * Lh + tid];

    for (int kt = 0; kt < nkt; ++kt) {
        __syncthreads();
        #pragma unroll
        for (int it = 0; it < 2; ++it) {
            int e = tid + it * 256;
            int row = e >> 3, g = e & 7;
            *(uint4*)&Ks[row][g * 8] = kx[it];
            union { uint4 raw; ushort_t us[8]; } vv;
            vv.raw = vx[it];
            int col = row ^ (g << 3);
            #pragma unroll
            for (int j = 0; j < 8; ++j) Vt[g * 8 + j][col] = vv.us[j];
        }
        if (!mode && tid < 64) fgs[tid] = (fgn - 1.0f) * 1e9f;
        __syncthreads();

        if (kt + 1 < nkt) {
            #pragma unroll
            for (int it = 0; it < 2; ++it) {
                int e = tid + it * 256;
                int row = e >> 3, g = e & 7;
                int tok = (kt + 1) * 64 + row;
                const ushort_t* base = QKV + (size_t)(b * Lh + tok) * QS + qoff + h * 64 + g * 8;
                kx[it] = *(const uint4*)(base + 768);
                vx[it] = *(const uint4*)(base + 1536);
            }
            if (tid < 64) fgn = fg[b * Lh + (kt + 1) * 64 + tid];
        }

        // S = Q K^T — K fragments shared across q-stripes
        f32x4 s4[2][4];
        #pragma unroll
        for (int s = 0; s < 2; ++s)
            #pragma unroll
            for (int j4 = 0; j4 < 4; ++j4) s4[s][j4] = (f32x4){0.f, 0.f, 0.f, 0.f};
        #pragma unroll
        for (int step = 0; step < 2; ++step) {
            bf16x8 bk[4];
            #pragma unroll
            for (int j4 = 0; j4 < 4; ++j4)
                bk[j4] = *(const bf16x8*)&Ks[j4 * 16 + l15][step * 32 + quad * 8];
            for (int s = 0; s < nstripe; ++s)
                #pragma unroll
                for (int j4 = 0; j4 < 4; ++j4)
                    s4[s][j4] = MFMA16(aq[s][step], bk[j4], s4[s][j4]);
        }
        // scale + mask + exp; write P stripes
        for (int s = 0; s < nstripe; ++s) {
            int p0 = mode ? wave * 16 : wave * 32 + s * 16;
            #pragma unroll
            for (int j4 = 0; j4 < 4; ++j4) {
                float mb = mode ? 0.0f : fgs[j4 * 16 + l15];
                #pragma unroll
                for (int r = 0; r < 4; ++r) {
                    float p = __expf(s4[s][j4][r] * 0.125f + mb);
                    l_part[s][r] += p;
                    Ps[p0 + quad * 4 + r][j4 * 16 + l15] = f2bf(p);
                }
            }
        }
        // PV — V fragments shared across q-stripes
        #pragma unroll
        for (int step = 0; step < 2; ++step) {
            bf16x8 bv[4];
            #pragma unroll
            for (int t4 = 0; t4 < 4; ++t4) {
                int dd = t4 * 16 + l15;
                int cb = ((step * 4 + quad) ^ ((dd >> 3) & 7)) * 8;
                bv[t4] = *(const bf16x8*)&Vt[dd][cb];
            }
            for (int s = 0; s < nstripe; ++s) {
                int p0 = mode ? wave * 16 : wave * 32 + s * 16;
                bf16x8 a = *(const bf16x8*)&Ps[p0 + l15][step * 32 + quad * 8];
                #pragma unroll
                for (int t4 = 0; t4 < 4; ++t4)
                    o_acc[s][t4] = MFMA16(a, bv[t4], o_acc[s][t4]);
            }
        }
    }

    // reduce l across 16-lane groups; epilogue
    for (int s = 0; s < nstripe; ++s) {
        #pragma unroll
        for (int r = 0; r < 4; ++r) {
            float v = l_part[s][r];
            #pragma unroll
            for (int off = 8; off >= 1; off >>= 1)
                v += __shfl_xor(v, off, 64);
            float inv = 1.0f / v;
            int ql = (mode ? wave * 16 : wave * 32 + s * 16) + quad * 4 + r;
            int tok = mode ? ((wi * 8 + (ql >> 3)) * 48 + wj * 8 + (ql & 7)) : tile * 128 + ql;
            #pragma unroll
            for (int t4 = 0; t4 < 4; ++t4)
                O[(size_t)(b * Lh + tok) * Ch + h * 64 + t4 * 16 + l15] =
                    f2bf(o_acc[s][t4][r] * inv);
        }
    }
}

// ---------------------------------------------------------------- launch
extern "C" void kernel_launch(void* const* d_in, const int* in_sizes, int n_in,
                              void* d_out, int out_size, void* d_ws, size_t ws_size,
                              hipStream_t stream)
{
    const float* x       = (const float*)d_in[0];
    const float* mask    = (const float*)d_in[1];
    const float* w_qkv_g = (const float*)d_in[2];
    const float* b_qkv_g = (const float*)d_in[3];
    const float* w_o_g   = (const float*)d_in[4];
    const float* b_o_g   = (const float*)d_in[5];
    const float* w_qkv_l = (const float*)d_in[6];
    const float* b_qkv_l = (const float*)d_in[7];
    const float* w_o_l   = (const float*)d_in[8];
    const float* b_o_l   = (const float*)d_in[9];
    const float* ln1_w   = (const float*)d_in[10];
    const float* ln1_b   = (const float*)d_in[11];
    const float* ln2_w   = (const float*)d_in[12];
    const float* ln2_b   = (const float*)d_in[13];
    const float* w_fc1   = (const float*)d_in[14];
    const float* b_fc1   = (const float*)d_in[15];
    const float* w_fc2   = (const float*)d_in[16];
    const float* b_fc2   = (const float*)d_in[17];
    float* out = (float*)d_out;

    const size_t U = (size_t)Bh * Lh * Ch;           // 3,538,944
    char* p = (char*)d_ws;
    ushort_t* qkvb = (ushort_t*)p;        p += (size_t)4608 * 4608 * 2;  // [4608][4608] bf16
    ushort_t* midb = qkvb;                                               // [4608][3072] aliases
    ushort_t* ctxb = (ushort_t*)p;        p += U * 2;
    ushort_t* xnb  = (ushort_t*)p;        p += U * 2;
    float*    x1   = (float*)p;           p += U * 4;
    ushort_t* wtq  = (ushort_t*)p;        p += (size_t)4608 * 768 * 2;   // qkv g|l concat
    ushort_t* wt_o_g = (ushort_t*)p;      p += (size_t)768 * 768 * 2;
    ushort_t* wt_o_l = (ushort_t*)p;      p += (size_t)768 * 768 * 2;
    ushort_t* wt_fc1 = (ushort_t*)p;      p += (size_t)3072 * 768 * 2;
    ushort_t* wt_fc2 = (ushort_t*)p;      p += (size_t)768 * 3072 * 2;
    float*    biasq  = (float*)p;         p += 4608 * 4;
    float*    fg     = (float*)p;         p += Bh * Lh * 4;
    float*    bgw    = (float*)p;

    const int Mrows = Bh * Lh;                   // 4608
    dim3 blk(256);

    // concat qkv biases (g then l)
    hipMemcpyAsync(biasq, b_qkv_g, 2304 * sizeof(float), hipMemcpyDeviceToDevice, stream);
    hipMemcpyAsync(biasq + 2304, b_qkv_l, 2304 * sizeof(float), hipMemcpyDeviceToDevice, stream);

    // weight cast+transpose
    for (int t = 0; t < 3; ++t) {
        transpose_cast_kernel<<<dim3(12, 12), blk, 0, stream>>>(
            w_qkv_g + (size_t)t * Ch * Ch, wtq + (size_t)t * Ch * Ch, Ch, Ch);
        transpose_cast_kernel<<<dim3(12, 12), blk, 0, stream>>>(
            w_qkv_l + (size_t)t * Ch * Ch, wtq + (size_t)(2304 + t * Ch) * Ch, Ch, Ch);
    }
    transpose_cast_kernel<<<dim3(12, 12), blk, 0, stream>>>(w_o_g, wt_o_g, Ch, Ch);
    transpose_cast_kernel<<<dim3(12, 12), blk, 0, stream>>>(w_o_l, wt_o_l, Ch, Ch);
    transpose_cast_kernel<<<dim3(48, 12), blk, 0, stream>>>(w_fc1, wt_fc1, Ch, 3072);
    transpose_cast_kernel<<<dim3(12, 48), blk, 0, stream>>>(w_fc2, wt_fc2, 3072, Ch);

    // LN1 -> bf16; masks
    layernorm_bf16_kernel<<<Mrows, blk, 0, stream>>>(x, ln1_w, ln1_b, xnb);
    mask_pool_kernel<<<(Bh * 48 * 48 + 255) / 256, blk, 0, stream>>>(mask, fg);
    mask_win_kernel<<<1, blk, 0, stream>>>(fg, bgw);

    // fused QKV GEMM for both branches (N=4608)
    gemm_bf16_t<128><<<dim3(4608 / 128, Mrows / 128), blk, 0, stream>>>(
        xnb, wtq, biasq, nullptr, qkvb, Mrows, 4608, Ch, 2, nullptr, nullptr);

    // global attention + masked o-proj into x1
    attn_mfma_kernel<<<dim3(18, NHh, Bh), blk, 0, stream>>>(qkvb, fg, ctxb, 0, 0);
    gemm_bf16_t<64><<<dim3(Ch / 64, Mrows / 128), blk, 0, stream>>>(
        ctxb, wt_o_g, b_o_g, x, x1, Mrows, Ch, Ch, 4, fg, nullptr);

    // local attention + masked o-proj accumulate into x1
    attn_mfma_kernel<<<dim3(36, NHh, Bh), blk, 0, stream>>>(qkvb, fg, ctxb, 1, 2304);
    gemm_bf16_t<64><<<dim3(Ch / 64, Mrows / 128), blk, 0, stream>>>(
        ctxb, wt_o_l, b_o_l, x1, x1, Mrows, Ch, Ch, 8, fg, bgw);

    // LN2 -> bf16
    layernorm_bf16_kernel<<<Mrows, blk, 0, stream>>>(x1, ln2_w, ln2_b, xnb);

    // MLP
    gemm_bf16_t<128><<<dim3(3072 / 128, Mrows / 128), blk, 0, stream>>>(
        xnb, wt_fc1, b_fc1, nullptr, midb, Mrows, 3072, Ch, 1 | 2, nullptr, nullptr);
    gemm_bf16_t<64><<<dim3(Ch / 64, Mrows / 128), blk, 0, stream>>>(
        midb, wt_fc2, b_fc2, x1, out, Mrows, Ch, 3072, 0, nullptr, nullptr);
}

// Round 6
// 546.633 us; speedup vs baseline: 2.1093x; 2.1093x over previous
//
#include <hip/hip_runtime.h>
#include <math.h>

#define Lh 2304
#define Ch 768
#define NHh 12
#define Bh 2
#define QS 4608   // row stride of fused qkv activation buffer (global q|k|v, local q|k|v)

typedef unsigned short ushort_t;
typedef unsigned int uint_t;
typedef __attribute__((ext_vector_type(8))) short bf16x8;
typedef __attribute__((ext_vector_type(4))) float f32x4;
#define MFMA16(a, b, c) __builtin_amdgcn_mfma_f32_16x16x32_bf16(a, b, c, 0, 0, 0)

__device__ __forceinline__ ushort_t f2bf(float f) {
    union { float f; uint_t u; } v; v.f = f;
    uint_t u = v.u + 0x7fffu + ((v.u >> 16) & 1u);   // RNE
    return (ushort_t)(u >> 16);
}

// ---------------------------------------------------------------- layernorm (fp32 in, bf16 out)
__global__ __launch_bounds__(256)
void layernorm_bf16_kernel(const float* __restrict__ x, const float* __restrict__ w,
                           const float* __restrict__ b, ushort_t* __restrict__ y)
{
    int row = blockIdx.x;
    int tid = threadIdx.x;
    const float* xr = x + (size_t)row * Ch;
    float v0 = xr[tid], v1 = xr[tid + 256], v2 = xr[tid + 512];
    __shared__ float red[256];
    red[tid] = v0 + v1 + v2;
    __syncthreads();
    for (int st = 128; st > 0; st >>= 1) {
        if (tid < st) red[tid] += red[tid + st];
        __syncthreads();
    }
    float mean = red[0] * (1.0f / 768.0f);
    __syncthreads();
    float d0 = v0 - mean, d1 = v1 - mean, d2 = v2 - mean;
    red[tid] = d0 * d0 + d1 * d1 + d2 * d2;
    __syncthreads();
    for (int st = 128; st > 0; st >>= 1) {
        if (tid < st) red[tid] += red[tid + st];
        __syncthreads();
    }
    float rstd = rsqrtf(red[0] * (1.0f / 768.0f) + 1e-6f);
    ushort_t* yr = y + (size_t)row * Ch;
    yr[tid]       = f2bf(d0 * rstd * w[tid]       + b[tid]);
    yr[tid + 256] = f2bf(d1 * rstd * w[tid + 256] + b[tid + 256]);
    yr[tid + 512] = f2bf(d2 * rstd * w[tid + 512] + b[tid + 512]);
}

// ---------------------------------------------------------------- mask pooling
__global__ __launch_bounds__(256)
void mask_pool_kernel(const float* __restrict__ mask, float* __restrict__ fg)
{
    int idx = blockIdx.x * 256 + threadIdx.x;
    if (idx >= Bh * 48 * 48) return;
    int b = idx / (48 * 48);
    int rem = idx % (48 * 48);
    int i = rem / 48, j = rem % 48;
    const float* mb = mask + (size_t)b * 192 * 192;
    float s = 0.0f;
    #pragma unroll
    for (int di = 0; di < 4; ++di)
        #pragma unroll
        for (int dj = 0; dj < 4; ++dj)
            s += mb[(i * 4 + di) * 192 + (j * 4 + dj)];
    fg[idx] = (s * (1.0f / 16.0f) > 0.4f) ? 1.0f : 0.0f;
}

__global__ __launch_bounds__(256)
void mask_win_kernel(const float* __restrict__ fg, float* __restrict__ bgw)
{
    int idx = blockIdx.x * 256 + threadIdx.x;
    if (idx >= Bh * 36) return;
    int b = idx / 36, rem = idx % 36;
    int wi = rem / 6, wj = rem % 6;
    float anybg = 0.0f;
    for (int r = 0; r < 8; ++r)
        for (int c = 0; c < 8; ++c) {
            int n = (wi * 8 + r) * 48 + wj * 8 + c;
            if (fg[b * Lh + n] == 0.0f) anybg = 1.0f;
        }
    bgw[idx] = anybg;
}

// ---------------------------------------------------------------- weight cast+transpose: W[K][N] f32 -> Wt[N][K] bf16
__global__ __launch_bounds__(256)
void transpose_cast_kernel(const float* __restrict__ W, ushort_t* __restrict__ Wt,
                           int K, int N)
{
    int n0 = blockIdx.x * 64;
    int k0 = blockIdx.y * 64;
    int tid = threadIdx.x;
    __shared__ float T[64][65];
    #pragma unroll
    for (int i = 0; i < 16; ++i) {
        int lin = i * 256 + tid;
        int r = lin >> 6, c = lin & 63;
        T[r][c] = W[(size_t)(k0 + r) * N + n0 + c];
    }
    __syncthreads();
    #pragma unroll
    for (int i = 0; i < 16; ++i) {
        int lin = i * 256 + tid;
        int r = lin >> 6, c = lin & 63;
        Wt[(size_t)(n0 + r) * K + k0 + c] = f2bf(T[c][r]);
    }
}

// ---------------------------------------------------------------- bf16 MFMA GEMM (BM=128, BN template)
// C[M,N] = act(A[M,K] @ Bt[N,K]^T + bias) [+residual] with optional row-masking.
// flags: 1=gelu, 2=bf16 out, 4=fg-masked add (C=res+fg[row]*v), 8=bg-local masked add
template<int BNt>
__global__ __launch_bounds__(256)
void gemm_bf16_t(const ushort_t* __restrict__ A, const ushort_t* __restrict__ Bt,
                 const float* __restrict__ bias, const float* __restrict__ residual,
                 void* __restrict__ C, int M, int N, int K, int flags,
                 const float* __restrict__ fg, const float* __restrict__ bgw)
{
    __shared__ ushort_t As[128][40];
    __shared__ ushort_t Bs[BNt][40];
    int bm = blockIdx.y * 128;
    int bn = blockIdx.x * BNt;
    int tid = threadIdx.x;
    int lane = tid & 63;
    int wave = tid >> 6;
    int wm = wave >> 1, wn = wave & 1;
    int quad = lane >> 4, l15 = lane & 15;
    constexpr int NJ = BNt / 32;     // frag cols per wave: 4 (BN=128) or 2 (BN=64)

    f32x4 acc[4][NJ];
    #pragma unroll
    for (int i = 0; i < 4; ++i)
        #pragma unroll
        for (int j = 0; j < NJ; ++j)
            acc[i][j] = (f32x4){0.f, 0.f, 0.f, 0.f};

    for (int k0 = 0; k0 < K; k0 += 32) {
        #pragma unroll
        for (int it = 0; it < 2; ++it) {
            int e = tid + it * 256;
            int row = e >> 2, g = e & 3;
            *(uint4*)&As[row][g * 8] = *(const uint4*)(A + (size_t)(bm + row) * K + k0 + g * 8);
        }
        #pragma unroll
        for (int it = 0; it < BNt / 64; ++it) {
            int e = tid + it * 256;
            int row = e >> 2, g = e & 3;
            *(uint4*)&Bs[row][g * 8] = *(const uint4*)(Bt + (size_t)(bn + row) * K + k0 + g * 8);
        }
        __syncthreads();
        bf16x8 af[4], bfr[NJ];
        #pragma unroll
        for (int i = 0; i < 4; ++i)
            af[i] = *(const bf16x8*)&As[wm * 64 + i * 16 + l15][quad * 8];
        #pragma unroll
        for (int j = 0; j < NJ; ++j)
            bfr[j] = *(const bf16x8*)&Bs[wn * (BNt / 2) + j * 16 + l15][quad * 8];
        #pragma unroll
        for (int i = 0; i < 4; ++i)
            #pragma unroll
            for (int j = 0; j < NJ; ++j)
                acc[i][j] = MFMA16(af[i], bfr[j], acc[i][j]);
        __syncthreads();
    }

    float bia[NJ];
    #pragma unroll
    for (int j = 0; j < NJ; ++j) bia[j] = bias[bn + wn * (BNt / 2) + j * 16 + l15];

    #pragma unroll
    for (int i = 0; i < 4; ++i) {
        #pragma unroll
        for (int r = 0; r < 4; ++r) {
            int row = bm + wm * 64 + i * 16 + quad * 4 + r;
            float keep = 1.0f;
            if (flags & 4) keep = (fg[row] != 0.0f) ? 1.0f : 0.0f;
            if (flags & 8) {
                int bb = (row >= Lh) ? 1 : 0;
                int n = row - bb * Lh;
                int ii = n / 48, jj = n % 48;
                keep = (fg[row] == 0.0f && bgw[bb * 36 + (ii >> 3) * 6 + (jj >> 3)] != 0.0f)
                           ? 1.0f : 0.0f;
            }
            #pragma unroll
            for (int j = 0; j < NJ; ++j) {
                int col = bn + wn * (BNt / 2) + j * 16 + l15;
                float v = acc[i][j][r] + bia[j];
                if (flags & 1) v = v * 0.5f * (1.0f + erff(v * 0.70710678f));
                float o;
                if (flags & (4 | 8)) o = residual[(size_t)row * N + col] + keep * v;
                else if (residual)   o = residual[(size_t)row * N + col] + v;
                else                 o = v;
                if (flags & 2) ((ushort_t*)C)[(size_t)row * N + col] = f2bf(o);
                else           ((float*)C)[(size_t)row * N + col] = o;
            }
        }
    }
}

// ---------------------------------------------------------------- MFMA flash attention (no-max softmax)
// Templated on MODE so all stripe loops unroll and register arrays stay in VGPRs
// (runtime-bounded loop in R5 forced dynamic indexing -> scratch -> 6x regression).
// MODE 0: 128-q tile, 36 key tiles, fg mask, grid (18,NH,B); wave owns 2 stripes of 16 q.
// MODE 1: 64-q window tile, 1 key tile, grid (36,NH,B); wave owns 1 stripe.
// Vt XOR-swizzled: Vt[d][tok ^ ((d>>3)<<3)] -> conflict-free transposed staging.
template<int MODE>
__global__ __launch_bounds__(256)
void attn_mfma_kernel(const ushort_t* __restrict__ QKV, const float* __restrict__ fg,
                      ushort_t* __restrict__ O, int qoff)
{
    constexpr int NS = MODE ? 1 : 2;           // q stripes per wave
    int tile = blockIdx.x;
    int h = blockIdx.y;
    int b = blockIdx.z;
    int tid = threadIdx.x;
    int lane = tid & 63;
    int wave = tid >> 6;
    int quad = lane >> 4, l15 = lane & 15;
    int wi = tile / 6, wj = tile % 6;          // local-mode window coords

    __shared__ ushort_t Ks[64][72];
    __shared__ ushort_t Vt[64][72];
    __shared__ ushort_t Ps[MODE ? 64 : 128][72];
    __shared__ float fgs[64];

    // Q fragments from global into registers (loop-invariant)
    bf16x8 aq[NS][2];
    #pragma unroll
    for (int s = 0; s < NS; ++s) {
        int ql = MODE ? (wave * 16 + l15) : (wave * 32 + s * 16 + l15);
        int tok = MODE ? ((wi * 8 + (ql >> 3)) * 48 + wj * 8 + (ql & 7)) : tile * 128 + ql;
        const ushort_t* qbase = QKV + (size_t)(b * Lh + tok) * QS + qoff + h * 64;
        #pragma unroll
        for (int step = 0; step < 2; ++step)
            aq[s][step] = *(const bf16x8*)(qbase + step * 32 + quad * 8);
    }

    float l_part[NS][4];
    f32x4 o_acc[NS][4];
    #pragma unroll
    for (int s = 0; s < NS; ++s)
        #pragma unroll
        for (int t4 = 0; t4 < 4; ++t4) {
            o_acc[s][t4] = (f32x4){0.f, 0.f, 0.f, 0.f};
            l_part[s][t4] = 0.f;
        }

    constexpr int nkt = MODE ? 1 : 36;

    // prefetch tile 0 K/V
    uint4 kx[2], vx[2];
    #pragma unroll
    for (int it = 0; it < 2; ++it) {
        int e = tid + it * 256;
        int row = e >> 3, g = e & 7;
        int tok = MODE ? ((wi * 8 + (row >> 3)) * 48 + wj * 8 + (row & 7)) : row;
        const ushort_t* base = QKV + (size_t)(b * Lh + tok) * QS + qoff + h * 64 + g * 8;
        kx[it] = *(const uint4*)(base + 768);
        vx[it] = *(const uint4*)(base + 1536);
    }
    float fgn = 0.f;
    if (!MODE && tid < 64) fgn = fg[b * Lh + tid];

    for (int kt = 0; kt < nkt; ++kt) {
        __syncthreads();
        #pragma unroll
        for (int it = 0; it < 2; ++it) {
            int e = tid + it * 256;
            int row = e >> 3, g = e & 7;
            *(uint4*)&Ks[row][g * 8] = kx[it];
            union { uint4 raw; ushort_t us[8]; } vv;
            vv.raw = vx[it];
            int col = row ^ (g << 3);
            #pragma unroll
            for (int j = 0; j < 8; ++j) Vt[g * 8 + j][col] = vv.us[j];
        }
        if (!MODE && tid < 64) fgs[tid] = (fgn - 1.0f) * 1e9f;
        __syncthreads();

        if (kt + 1 < nkt) {
            #pragma unroll
            for (int it = 0; it < 2; ++it) {
                int e = tid + it * 256;
                int row = e >> 3, g = e & 7;
                int tok = (kt + 1) * 64 + row;
                const ushort_t* base = QKV + (size_t)(b * Lh + tok) * QS + qoff + h * 64 + g * 8;
                kx[it] = *(const uint4*)(base + 768);
                vx[it] = *(const uint4*)(base + 1536);
            }
            if (tid < 64) fgn = fg[b * Lh + (kt + 1) * 64 + tid];
        }

        // S = Q K^T — K fragments shared across q-stripes
        f32x4 s4[NS][4];
        #pragma unroll
        for (int s = 0; s < NS; ++s)
            #pragma unroll
            for (int j4 = 0; j4 < 4; ++j4) s4[s][j4] = (f32x4){0.f, 0.f, 0.f, 0.f};
        #pragma unroll
        for (int step = 0; step < 2; ++step) {
            bf16x8 bk[4];
            #pragma unroll
            for (int j4 = 0; j4 < 4; ++j4)
                bk[j4] = *(const bf16x8*)&Ks[j4 * 16 + l15][step * 32 + quad * 8];
            #pragma unroll
            for (int s = 0; s < NS; ++s)
                #pragma unroll
                for (int j4 = 0; j4 < 4; ++j4)
                    s4[s][j4] = MFMA16(aq[s][step], bk[j4], s4[s][j4]);
        }
        // scale + mask + exp; write P stripes
        #pragma unroll
        for (int s = 0; s < NS; ++s) {
            int p0 = MODE ? wave * 16 : wave * 32 + s * 16;
            #pragma unroll
            for (int j4 = 0; j4 < 4; ++j4) {
                float mb = MODE ? 0.0f : fgs[j4 * 16 + l15];
                #pragma unroll
                for (int r = 0; r < 4; ++r) {
                    float p = __expf(s4[s][j4][r] * 0.125f + mb);
                    l_part[s][r] += p;
                    Ps[p0 + quad * 4 + r][j4 * 16 + l15] = f2bf(p);
                }
            }
        }
        // PV — V fragments shared across q-stripes
        #pragma unroll
        for (int step = 0; step < 2; ++step) {
            bf16x8 bv[4];
            #pragma unroll
            for (int t4 = 0; t4 < 4; ++t4) {
                int dd = t4 * 16 + l15;
                int cb = ((step * 4 + quad) ^ ((dd >> 3) & 7)) * 8;
                bv[t4] = *(const bf16x8*)&Vt[dd][cb];
            }
            #pragma unroll
            for (int s = 0; s < NS; ++s) {
                int p0 = MODE ? wave * 16 : wave * 32 + s * 16;
                bf16x8 a = *(const bf16x8*)&Ps[p0 + l15][step * 32 + quad * 8];
                #pragma unroll
                for (int t4 = 0; t4 < 4; ++t4)
                    o_acc[s][t4] = MFMA16(a, bv[t4], o_acc[s][t4]);
            }
        }
    }

    // reduce l across 16-lane groups; epilogue
    #pragma unroll
    for (int s = 0; s < NS; ++s) {
        #pragma unroll
        for (int r = 0; r < 4; ++r) {
            float v = l_part[s][r];
            #pragma unroll
            for (int off = 8; off >= 1; off >>= 1)
                v += __shfl_xor(v, off, 64);
            float inv = 1.0f / v;
            int ql = (MODE ? wave * 16 : wave * 32 + s * 16) + quad * 4 + r;
            int tok = MODE ? ((wi * 8 + (ql >> 3)) * 48 + wj * 8 + (ql & 7)) : tile * 128 + ql;
            #pragma unroll
            for (int t4 = 0; t4 < 4; ++t4)
                O[(size_t)(b * Lh + tok) * Ch + h * 64 + t4 * 16 + l15] =
                    f2bf(o_acc[s][t4][r] * inv);
        }
    }
}

// ---------------------------------------------------------------- launch
extern "C" void kernel_launch(void* const* d_in, const int* in_sizes, int n_in,
                              void* d_out, int out_size, void* d_ws, size_t ws_size,
                              hipStream_t stream)
{
    const float* x       = (const float*)d_in[0];
    const float* mask    = (const float*)d_in[1];
    const float* w_qkv_g = (const float*)d_in[2];
    const float* b_qkv_g = (const float*)d_in[3];
    const float* w_o_g   = (const float*)d_in[4];
    const float* b_o_g   = (const float*)d_in[5];
    const float* w_qkv_l = (const float*)d_in[6];
    const float* b_qkv_l = (const float*)d_in[7];
    const float* w_o_l   = (const float*)d_in[8];
    const float* b_o_l   = (const float*)d_in[9];
    const float* ln1_w   = (const float*)d_in[10];
    const float* ln1_b   = (const float*)d_in[11];
    const float* ln2_w   = (const float*)d_in[12];
    const float* ln2_b   = (const float*)d_in[13];
    const float* w_fc1   = (const float*)d_in[14];
    const float* b_fc1   = (const float*)d_in[15];
    const float* w_fc2   = (const float*)d_in[16];
    const float* b_fc2   = (const float*)d_in[17];
    float* out = (float*)d_out;

    const size_t U = (size_t)Bh * Lh * Ch;           // 3,538,944
    char* p = (char*)d_ws;
    ushort_t* qkvb = (ushort_t*)p;        p += (size_t)4608 * 4608 * 2;  // [4608][4608] bf16
    ushort_t* midb = qkvb;                                               // [4608][3072] aliases
    ushort_t* ctxb = (ushort_t*)p;        p += U * 2;
    ushort_t* xnb  = (ushort_t*)p;        p += U * 2;
    float*    x1   = (float*)p;           p += U * 4;
    ushort_t* wtq  = (ushort_t*)p;        p += (size_t)4608 * 768 * 2;   // qkv g|l concat
    ushort_t* wt_o_g = (ushort_t*)p;      p += (size_t)768 * 768 * 2;
    ushort_t* wt_o_l = (ushort_t*)p;      p += (size_t)768 * 768 * 2;
    ushort_t* wt_fc1 = (ushort_t*)p;      p += (size_t)3072 * 768 * 2;
    ushort_t* wt_fc2 = (ushort_t*)p;      p += (size_t)768 * 3072 * 2;
    float*    biasq  = (float*)p;         p += 4608 * 4;
    float*    fg     = (float*)p;         p += Bh * Lh * 4;
    float*    bgw    = (float*)p;

    const int Mrows = Bh * Lh;                   // 4608
    dim3 blk(256);

    // concat qkv biases (g then l)
    hipMemcpyAsync(biasq, b_qkv_g, 2304 * sizeof(float), hipMemcpyDeviceToDevice, stream);
    hipMemcpyAsync(biasq + 2304, b_qkv_l, 2304 * sizeof(float), hipMemcpyDeviceToDevice, stream);

    // weight cast+transpose
    for (int t = 0; t < 3; ++t) {
        transpose_cast_kernel<<<dim3(12, 12), blk, 0, stream>>>(
            w_qkv_g + (size_t)t * Ch * Ch, wtq + (size_t)t * Ch * Ch, Ch, Ch);
        transpose_cast_kernel<<<dim3(12, 12), blk, 0, stream>>>(
            w_qkv_l + (size_t)t * Ch * Ch, wtq + (size_t)(2304 + t * Ch) * Ch, Ch, Ch);
    }
    transpose_cast_kernel<<<dim3(12, 12), blk, 0, stream>>>(w_o_g, wt_o_g, Ch, Ch);
    transpose_cast_kernel<<<dim3(12, 12), blk, 0, stream>>>(w_o_l, wt_o_l, Ch, Ch);
    transpose_cast_kernel<<<dim3(48, 12), blk, 0, stream>>>(w_fc1, wt_fc1, Ch, 3072);
    transpose_cast_kernel<<<dim3(12, 48), blk, 0, stream>>>(w_fc2, wt_fc2, 3072, Ch);

    // LN1 -> bf16; masks
    layernorm_bf16_kernel<<<Mrows, blk, 0, stream>>>(x, ln1_w, ln1_b, xnb);
    mask_pool_kernel<<<(Bh * 48 * 48 + 255) / 256, blk, 0, stream>>>(mask, fg);
    mask_win_kernel<<<1, blk, 0, stream>>>(fg, bgw);

    // fused QKV GEMM for both branches (N=4608)
    gemm_bf16_t<128><<<dim3(4608 / 128, Mrows / 128), blk, 0, stream>>>(
        xnb, wtq, biasq, nullptr, qkvb, Mrows, 4608, Ch, 2, nullptr, nullptr);

    // global attention + masked o-proj into x1
    attn_mfma_kernel<0><<<dim3(18, NHh, Bh), blk, 0, stream>>>(qkvb, fg, ctxb, 0);
    gemm_bf16_t<64><<<dim3(Ch / 64, Mrows / 128), blk, 0, stream>>>(
        ctxb, wt_o_g, b_o_g, x, x1, Mrows, Ch, Ch, 4, fg, nullptr);

    // local attention + masked o-proj accumulate into x1
    attn_mfma_kernel<1><<<dim3(36, NHh, Bh), blk, 0, stream>>>(qkvb, fg, ctxb, 2304);
    gemm_bf16_t<64><<<dim3(Ch / 64, Mrows / 128), blk, 0, stream>>>(
        ctxb, wt_o_l, b_o_l, x1, x1, Mrows, Ch, Ch, 8, fg, bgw);

    // LN2 -> bf16
    layernorm_bf16_kernel<<<Mrows, blk, 0, stream>>>(x1, ln2_w, ln2_b, xnb);

    // MLP
    gemm_bf16_t<128><<<dim3(3072 / 128, Mrows / 128), blk, 0, stream>>>(
        xnb, wt_fc1, b_fc1, nullptr, midb, Mrows, 3072, Ch, 1 | 2, nullptr, nullptr);
    gemm_bf16_t<64><<<dim3(Ch / 64, Mrows / 128), blk, 0, stream>>>(
        midb, wt_fc2, b_fc2, x1, out, Mrows, Ch, 3072, 0, nullptr, nullptr);
}

// Round 7
// 507.661 us; speedup vs baseline: 2.2713x; 1.0768x over previous
//
#include <hip/hip_runtime.h>
#include <math.h>

#define Lh 2304
#define Ch 768
#define NHh 12
#define Bh 2
#define QS 4608   // row stride of fused qkv activation buffer (global q|k|v, local q|k|v)

typedef unsigned short ushort_t;
typedef unsigned int uint_t;
typedef __attribute__((ext_vector_type(8))) short bf16x8;
typedef __attribute__((ext_vector_type(4))) float f32x4;
#define MFMA16(a, b, c) __builtin_amdgcn_mfma_f32_16x16x32_bf16(a, b, c, 0, 0, 0)

__device__ __forceinline__ ushort_t f2bf(float f) {
    union { float f; uint_t u; } v; v.f = f;
    uint_t u = v.u + 0x7fffu + ((v.u >> 16) & 1u);   // RNE
    return (ushort_t)(u >> 16);
}

// async global->LDS, 16B/lane, dest = wave-uniform base + lane*16
__device__ __forceinline__ void llds16(ushort_t* dst, const ushort_t* src) {
    __builtin_amdgcn_global_load_lds(
        (__attribute__((address_space(1))) void*)(const_cast<ushort_t*>(src)),
        (__attribute__((address_space(3))) void*)dst, 16, 0, 0);
}

// ---------------------------------------------------------------- layernorm (fp32 in, bf16 out)
__global__ __launch_bounds__(256)
void layernorm_bf16_kernel(const float* __restrict__ x, const float* __restrict__ w,
                           const float* __restrict__ b, ushort_t* __restrict__ y)
{
    int row = blockIdx.x;
    int tid = threadIdx.x;
    const float* xr = x + (size_t)row * Ch;
    float v0 = xr[tid], v1 = xr[tid + 256], v2 = xr[tid + 512];
    __shared__ float red[256];
    red[tid] = v0 + v1 + v2;
    __syncthreads();
    for (int st = 128; st > 0; st >>= 1) {
        if (tid < st) red[tid] += red[tid + st];
        __syncthreads();
    }
    float mean = red[0] * (1.0f / 768.0f);
    __syncthreads();
    float d0 = v0 - mean, d1 = v1 - mean, d2 = v2 - mean;
    red[tid] = d0 * d0 + d1 * d1 + d2 * d2;
    __syncthreads();
    for (int st = 128; st > 0; st >>= 1) {
        if (tid < st) red[tid] += red[tid + st];
        __syncthreads();
    }
    float rstd = rsqrtf(red[0] * (1.0f / 768.0f) + 1e-6f);
    ushort_t* yr = y + (size_t)row * Ch;
    yr[tid]       = f2bf(d0 * rstd * w[tid]       + b[tid]);
    yr[tid + 256] = f2bf(d1 * rstd * w[tid + 256] + b[tid + 256]);
    yr[tid + 512] = f2bf(d2 * rstd * w[tid + 512] + b[tid + 512]);
}

// ---------------------------------------------------------------- fused mask kernel
// 72 blocks (one wave per window): pooled fg per token + window "any bg" via ballot
__global__ __launch_bounds__(64)
void mask_kernel(const float* __restrict__ mask, float* __restrict__ fg,
                 float* __restrict__ bgw)
{
    int win = blockIdx.x;            // 0..71
    int b = win / 36, w = win % 36;
    int wi = w / 6, wj = w % 6;
    int lane = threadIdx.x;          // 64
    int i = wi * 8 + (lane >> 3), j = wj * 8 + (lane & 7);
    const float* mb = mask + (size_t)b * 192 * 192 + (size_t)(i * 4) * 192 + j * 4;
    float s = 0.0f;
    #pragma unroll
    for (int di = 0; di < 4; ++di) {
        float4 v = *(const float4*)(mb + (size_t)di * 192);
        s += v.x + v.y + v.z + v.w;
    }
    float f = (s * (1.0f / 16.0f) > 0.4f) ? 1.0f : 0.0f;
    fg[b * Lh + i * 48 + j] = f;
    unsigned long long bg = __ballot(f == 0.0f);
    if (lane == 0) bgw[win] = bg ? 1.0f : 0.0f;
}

// ---------------------------------------------------------------- batched weight cast+transpose
// one dispatch for all 6 weights; W[K][N] f32 -> Wt[N][K] bf16, 64x64 tiles
__global__ __launch_bounds__(256)
void transpose_all_kernel(const float* __restrict__ w_qkv_g, const float* __restrict__ w_qkv_l,
                          const float* __restrict__ w_o_g, const float* __restrict__ w_o_l,
                          const float* __restrict__ w_fc1, const float* __restrict__ w_fc2,
                          ushort_t* __restrict__ wtq, ushort_t* __restrict__ wt_o_g,
                          ushort_t* __restrict__ wt_o_l, ushort_t* __restrict__ wt_fc1,
                          ushort_t* __restrict__ wt_fc2)
{
    int blk = blockIdx.x;
    const float* W; ushort_t* D; int K, N, nx, bx;
    const size_t CC = (size_t)Ch * Ch;
    if (blk < 432)       { int t = blk / 144; bx = blk % 144;
                           W = w_qkv_g + t * CC; D = wtq + t * CC; K = 768; N = 768; nx = 12; }
    else if (blk < 864)  { int r = blk - 432; int t = r / 144; bx = r % 144;
                           W = w_qkv_l + t * CC; D = wtq + (size_t)2304 * 768 + t * CC;
                           K = 768; N = 768; nx = 12; }
    else if (blk < 1008) { bx = blk - 864;  W = w_o_g; D = wt_o_g; K = 768; N = 768; nx = 12; }
    else if (blk < 1152) { bx = blk - 1008; W = w_o_l; D = wt_o_l; K = 768; N = 768; nx = 12; }
    else if (blk < 1728) { bx = blk - 1152; W = w_fc1; D = wt_fc1; K = 768; N = 3072; nx = 48; }
    else                 { bx = blk - 1728; W = w_fc2; D = wt_fc2; K = 3072; N = 768; nx = 12; }
    int n0 = (bx % nx) * 64;
    int k0 = (bx / nx) * 64;
    int tid = threadIdx.x;
    __shared__ float T[64][65];
    #pragma unroll
    for (int i = 0; i < 16; ++i) {
        int lin = i * 256 + tid;
        int r = lin >> 6, c = lin & 63;
        T[r][c] = W[(size_t)(k0 + r) * N + n0 + c];
    }
    __syncthreads();
    #pragma unroll
    for (int i = 0; i < 16; ++i) {
        int lin = i * 256 + tid;
        int r = lin >> 6, c = lin & 63;
        D[(size_t)(n0 + r) * K + k0 + c] = f2bf(T[c][r]);
    }
}

// ---------------------------------------------------------------- bf16 MFMA GEMM (BM=128, BN template)
// global_load_lds staging, unpadded LDS with XOR chunk swizzle (realized via src addr):
//   LDS slot (row, cp) holds source chunk g = cp ^ ((row>>1)&3); fragment read uses
//   cp = quad ^ ((l15>>1)&3) -> max 2-way bank aliasing (free, m136).
// flags: 1=gelu, 2=bf16 out, 4=fg-masked add, 8=bg-local masked add
template<int BNt>
__global__ __launch_bounds__(256)
void gemm_bf16_t(const ushort_t* __restrict__ A, const ushort_t* __restrict__ Bt,
                 const float* __restrict__ bias, const float* __restrict__ residual,
                 void* __restrict__ C, int M, int N, int K, int flags,
                 const float* __restrict__ fg, const float* __restrict__ bgw)
{
    __shared__ ushort_t AsL[128 * 32];
    __shared__ ushort_t BsL[BNt * 32];
    int bm = blockIdx.y * 128;
    int bn = blockIdx.x * BNt;
    int tid = threadIdx.x;
    int lane = tid & 63;
    int wave = tid >> 6;
    int wm = wave >> 1, wn = wave & 1;
    int quad = lane >> 4, l15 = lane & 15;
    constexpr int NJ = BNt / 32;     // frag cols per wave: 4 (BN=128) or 2 (BN=64)

    // staging lane map: chunk c covers rows c*16+(lane>>2); lane fetches source chunk g
    int srow = lane >> 2;
    int sg8 = ((lane & 3) ^ ((lane >> 3) & 3)) * 8;
    int fsw = (l15 >> 1) & 3;

    f32x4 acc[4][NJ];
    #pragma unroll
    for (int i = 0; i < 4; ++i)
        #pragma unroll
        for (int j = 0; j < NJ; ++j)
            acc[i][j] = (f32x4){0.f, 0.f, 0.f, 0.f};

    for (int k0 = 0; k0 < K; k0 += 32) {
        __syncthreads();
        // As: 8 chunks of 1 KiB; wave w stages chunks w and w+4
        llds16(&AsL[wave * 512],
               A + (size_t)(bm + wave * 16 + srow) * K + k0 + sg8);
        llds16(&AsL[(wave + 4) * 512],
               A + (size_t)(bm + (wave + 4) * 16 + srow) * K + k0 + sg8);
        // Bs
        llds16(&BsL[wave * 512],
               Bt + (size_t)(bn + wave * 16 + srow) * K + k0 + sg8);
        if (BNt == 128)
            llds16(&BsL[(wave + 4) * 512],
                   Bt + (size_t)(bn + (wave + 4) * 16 + srow) * K + k0 + sg8);
        __syncthreads();   // drains vmcnt before barrier

        bf16x8 af[4], bfr[NJ];
        #pragma unroll
        for (int i = 0; i < 4; ++i)
            af[i] = *(const bf16x8*)&AsL[(wm * 64 + i * 16 + l15) * 32 + ((quad ^ fsw) * 8)];
        #pragma unroll
        for (int j = 0; j < NJ; ++j)
            bfr[j] = *(const bf16x8*)&BsL[(wn * (BNt / 2) + j * 16 + l15) * 32 + ((quad ^ fsw) * 8)];
        #pragma unroll
        for (int i = 0; i < 4; ++i)
            #pragma unroll
            for (int j = 0; j < NJ; ++j)
                acc[i][j] = MFMA16(af[i], bfr[j], acc[i][j]);
    }

    float bia[NJ];
    #pragma unroll
    for (int j = 0; j < NJ; ++j) bia[j] = bias[bn + wn * (BNt / 2) + j * 16 + l15];

    #pragma unroll
    for (int i = 0; i < 4; ++i) {
        #pragma unroll
        for (int r = 0; r < 4; ++r) {
            int row = bm + wm * 64 + i * 16 + quad * 4 + r;
            float keep = 1.0f;
            if (flags & 4) keep = (fg[row] != 0.0f) ? 1.0f : 0.0f;
            if (flags & 8) {
                int bb = (row >= Lh) ? 1 : 0;
                int n = row - bb * Lh;
                int ii = n / 48, jj = n % 48;
                keep = (fg[row] == 0.0f && bgw[bb * 36 + (ii >> 3) * 6 + (jj >> 3)] != 0.0f)
                           ? 1.0f : 0.0f;
            }
            #pragma unroll
            for (int j = 0; j < NJ; ++j) {
                int col = bn + wn * (BNt / 2) + j * 16 + l15;
                float v = acc[i][j][r] + bia[j];
                if (flags & 1) v = v * 0.5f * (1.0f + erff(v * 0.70710678f));
                float o;
                if (flags & (4 | 8)) o = residual[(size_t)row * N + col] + keep * v;
                else if (residual)   o = residual[(size_t)row * N + col] + v;
                else                 o = v;
                if (flags & 2) ((ushort_t*)C)[(size_t)row * N + col] = f2bf(o);
                else           ((float*)C)[(size_t)row * N + col] = o;
            }
        }
    }
}

// ---------------------------------------------------------------- MFMA flash attention (no-max softmax)
// MODE 0: 128-q tile, 36 key tiles, fg mask, grid (18,NH,B); wave owns 2 stripes of 16 q.
// MODE 1: 64-q window tile, 1 key tile, grid (36,NH,B); wave owns 1 stripe.
// Vt XOR-swizzled: Vt[d][tok ^ ((d>>3)<<3)] -> conflict-free transposed staging.
template<int MODE>
__global__ __launch_bounds__(256)
void attn_mfma_kernel(const ushort_t* __restrict__ QKV, const float* __restrict__ fg,
                      ushort_t* __restrict__ O, int qoff)
{
    constexpr int NS = MODE ? 1 : 2;           // q stripes per wave
    int tile = blockIdx.x;
    int h = blockIdx.y;
    int b = blockIdx.z;
    int tid = threadIdx.x;
    int lane = tid & 63;
    int wave = tid >> 6;
    int quad = lane >> 4, l15 = lane & 15;
    int wi = tile / 6, wj = tile % 6;          // local-mode window coords

    __shared__ ushort_t Ks[64][72];
    __shared__ ushort_t Vt[64][72];
    __shared__ ushort_t Ps[MODE ? 64 : 128][72];
    __shared__ float fgs[64];

    // Q fragments from global into registers (loop-invariant)
    bf16x8 aq[NS][2];
    #pragma unroll
    for (int s = 0; s < NS; ++s) {
        int ql = MODE ? (wave * 16 + l15) : (wave * 32 + s * 16 + l15);
        int tok = MODE ? ((wi * 8 + (ql >> 3)) * 48 + wj * 8 + (ql & 7)) : tile * 128 + ql;
        const ushort_t* qbase = QKV + (size_t)(b * Lh + tok) * QS + qoff + h * 64;
        #pragma unroll
        for (int step = 0; step < 2; ++step)
            aq[s][step] = *(const bf16x8*)(qbase + step * 32 + quad * 8);
    }

    float l_part[NS][4];
    f32x4 o_acc[NS][4];
    #pragma unroll
    for (int s = 0; s < NS; ++s)
        #pragma unroll
        for (int t4 = 0; t4 < 4; ++t4) {
            o_acc[s][t4] = (f32x4){0.f, 0.f, 0.f, 0.f};
            l_part[s][t4] = 0.f;
        }

    constexpr int nkt = MODE ? 1 : 36;

    // prefetch tile 0 K/V
    uint4 kx[2], vx[2];
    #pragma unroll
    for (int it = 0; it < 2; ++it) {
        int e = tid + it * 256;
        int row = e >> 3, g = e & 7;
        int tok = MODE ? ((wi * 8 + (row >> 3)) * 48 + wj * 8 + (row & 7)) : row;
        const ushort_t* base = QKV + (size_t)(b * Lh + tok) * QS + qoff + h * 64 + g * 8;
        kx[it] = *(const uint4*)(base + 768);
        vx[it] = *(const uint4*)(base + 1536);
    }
    float fgn = 0.f;
    if (!MODE && tid < 64) fgn = fg[b * Lh + tid];

    for (int kt = 0; kt < nkt; ++kt) {
        __syncthreads();
        #pragma unroll
        for (int it = 0; it < 2; ++it) {
            int e = tid + it * 256;
            int row = e >> 3, g = e & 7;
            *(uint4*)&Ks[row][g * 8] = kx[it];
            union { uint4 raw; ushort_t us[8]; } vv;
            vv.raw = vx[it];
            int col = row ^ (g << 3);
            #pragma unroll
            for (int j = 0; j < 8; ++j) Vt[g * 8 + j][col] = vv.us[j];
        }
        if (!MODE && tid < 64) fgs[tid] = (fgn - 1.0f) * 1e9f;
        __syncthreads();

        if (kt + 1 < nkt) {
            #pragma unroll
            for (int it = 0; it < 2; ++it) {
                int e = tid + it * 256;
                int row = e >> 3, g = e & 7;
                int tok = (kt + 1) * 64 + row;
                const ushort_t* base = QKV + (size_t)(b * Lh + tok) * QS + qoff + h * 64 + g * 8;
                kx[it] = *(const uint4*)(base + 768);
                vx[it] = *(const uint4*)(base + 1536);
            }
            if (tid < 64) fgn = fg[b * Lh + (kt + 1) * 64 + tid];
        }

        // S = Q K^T — K fragments shared across q-stripes
        f32x4 s4[NS][4];
        #pragma unroll
        for (int s = 0; s < NS; ++s)
            #pragma unroll
            for (int j4 = 0; j4 < 4; ++j4) s4[s][j4] = (f32x4){0.f, 0.f, 0.f, 0.f};
        #pragma unroll
        for (int step = 0; step < 2; ++step) {
            bf16x8 bk[4];
            #pragma unroll
            for (int j4 = 0; j4 < 4; ++j4)
                bk[j4] = *(const bf16x8*)&Ks[j4 * 16 + l15][step * 32 + quad * 8];
            #pragma unroll
            for (int s = 0; s < NS; ++s)
                #pragma unroll
                for (int j4 = 0; j4 < 4; ++j4)
                    s4[s][j4] = MFMA16(aq[s][step], bk[j4], s4[s][j4]);
        }
        // scale + mask + exp; write P stripes
        #pragma unroll
        for (int s = 0; s < NS; ++s) {
            int p0 = MODE ? wave * 16 : wave * 32 + s * 16;
            #pragma unroll
            for (int j4 = 0; j4 < 4; ++j4) {
                float mb = MODE ? 0.0f : fgs[j4 * 16 + l15];
                #pragma unroll
                for (int r = 0; r < 4; ++r) {
                    float p = __expf(s4[s][j4][r] * 0.125f + mb);
                    l_part[s][r] += p;
                    Ps[p0 + quad * 4 + r][j4 * 16 + l15] = f2bf(p);
                }
            }
        }
        // PV — V fragments shared across q-stripes
        #pragma unroll
        for (int step = 0; step < 2; ++step) {
            bf16x8 bv[4];
            #pragma unroll
            for (int t4 = 0; t4 < 4; ++t4) {
                int dd = t4 * 16 + l15;
                int cb = ((step * 4 + quad) ^ ((dd >> 3) & 7)) * 8;
                bv[t4] = *(const bf16x8*)&Vt[dd][cb];
            }
            #pragma unroll
            for (int s = 0; s < NS; ++s) {
                int p0 = MODE ? wave * 16 : wave * 32 + s * 16;
                bf16x8 a = *(const bf16x8*)&Ps[p0 + l15][step * 32 + quad * 8];
                #pragma unroll
                for (int t4 = 0; t4 < 4; ++t4)
                    o_acc[s][t4] = MFMA16(a, bv[t4], o_acc[s][t4]);
            }
        }
    }

    // reduce l across 16-lane groups; epilogue
    #pragma unroll
    for (int s = 0; s < NS; ++s) {
        #pragma unroll
        for (int r = 0; r < 4; ++r) {
            float v = l_part[s][r];
            #pragma unroll
            for (int off = 8; off >= 1; off >>= 1)
                v += __shfl_xor(v, off, 64);
            float inv = 1.0f / v;
            int ql = (MODE ? wave * 16 : wave * 32 + s * 16) + quad * 4 + r;
            int tok = MODE ? ((wi * 8 + (ql >> 3)) * 48 + wj * 8 + (ql & 7)) : tile * 128 + ql;
            #pragma unroll
            for (int t4 = 0; t4 < 4; ++t4)
                O[(size_t)(b * Lh + tok) * Ch + h * 64 + t4 * 16 + l15] =
                    f2bf(o_acc[s][t4][r] * inv);
        }
    }
}

// ---------------------------------------------------------------- launch
extern "C" void kernel_launch(void* const* d_in, const int* in_sizes, int n_in,
                              void* d_out, int out_size, void* d_ws, size_t ws_size,
                              hipStream_t stream)
{
    const float* x       = (const float*)d_in[0];
    const float* mask    = (const float*)d_in[1];
    const float* w_qkv_g = (const float*)d_in[2];
    const float* b_qkv_g = (const float*)d_in[3];
    const float* w_o_g   = (const float*)d_in[4];
    const float* b_o_g   = (const float*)d_in[5];
    const float* w_qkv_l = (const float*)d_in[6];
    const float* b_qkv_l = (const float*)d_in[7];
    const float* w_o_l   = (const float*)d_in[8];
    const float* b_o_l   = (const float*)d_in[9];
    const float* ln1_w   = (const float*)d_in[10];
    const float* ln1_b   = (const float*)d_in[11];
    const float* ln2_w   = (const float*)d_in[12];
    const float* ln2_b   = (const float*)d_in[13];
    const float* w_fc1   = (const float*)d_in[14];
    const float* b_fc1   = (const float*)d_in[15];
    const float* w_fc2   = (const float*)d_in[16];
    const float* b_fc2   = (const float*)d_in[17];
    float* out = (float*)d_out;

    const size_t U = (size_t)Bh * Lh * Ch;           // 3,538,944
    char* p = (char*)d_ws;
    ushort_t* qkvb = (ushort_t*)p;        p += (size_t)4608 * 4608 * 2;  // [4608][4608] bf16
    ushort_t* midb = qkvb;                                               // [4608][3072] aliases
    ushort_t* ctxb = (ushort_t*)p;        p += U * 2;
    ushort_t* xnb  = (ushort_t*)p;        p += U * 2;
    float*    x1   = (float*)p;           p += U * 4;
    ushort_t* wtq  = (ushort_t*)p;        p += (size_t)4608 * 768 * 2;   // qkv g|l concat
    ushort_t* wt_o_g = (ushort_t*)p;      p += (size_t)768 * 768 * 2;
    ushort_t* wt_o_l = (ushort_t*)p;      p += (size_t)768 * 768 * 2;
    ushort_t* wt_fc1 = (ushort_t*)p;      p += (size_t)3072 * 768 * 2;
    ushort_t* wt_fc2 = (ushort_t*)p;      p += (size_t)768 * 3072 * 2;
    float*    biasq  = (float*)p;         p += 4608 * 4;
    float*    fg     = (float*)p;         p += Bh * Lh * 4;
    float*    bgw    = (float*)p;

    const int Mrows = Bh * Lh;                   // 4608
    dim3 blk(256);

    // concat qkv biases (g then l)
    hipMemcpyAsync(biasq, b_qkv_g, 2304 * sizeof(float), hipMemcpyDeviceToDevice, stream);
    hipMemcpyAsync(biasq + 2304, b_qkv_l, 2304 * sizeof(float), hipMemcpyDeviceToDevice, stream);

    // all weight transposes in one dispatch
    transpose_all_kernel<<<2304, blk, 0, stream>>>(
        w_qkv_g, w_qkv_l, w_o_g, w_o_l, w_fc1, w_fc2,
        wtq, wt_o_g, wt_o_l, wt_fc1, wt_fc2);

    // LN1 -> bf16; fused masks
    layernorm_bf16_kernel<<<Mrows, blk, 0, stream>>>(x, ln1_w, ln1_b, xnb);
    mask_kernel<<<72, dim3(64), 0, stream>>>(mask, fg, bgw);

    // fused QKV GEMM for both branches (N=4608)
    gemm_bf16_t<128><<<dim3(4608 / 128, Mrows / 128), blk, 0, stream>>>(
        xnb, wtq, biasq, nullptr, qkvb, Mrows, 4608, Ch, 2, nullptr, nullptr);

    // global attention + masked o-proj into x1
    attn_mfma_kernel<0><<<dim3(18, NHh, Bh), blk, 0, stream>>>(qkvb, fg, ctxb, 0);
    gemm_bf16_t<64><<<dim3(Ch / 64, Mrows / 128), blk, 0, stream>>>(
        ctxb, wt_o_g, b_o_g, x, x1, Mrows, Ch, Ch, 4, fg, nullptr);

    // local attention + masked o-proj accumulate into x1
    attn_mfma_kernel<1><<<dim3(36, NHh, Bh), blk, 0, stream>>>(qkvb, fg, ctxb, 2304);
    gemm_bf16_t<64><<<dim3(Ch / 64, Mrows / 128), blk, 0, stream>>>(
        ctxb, wt_o_l, b_o_l, x1, x1, Mrows, Ch, Ch, 8, fg, bgw);

    // LN2 -> bf16
    layernorm_bf16_kernel<<<Mrows, blk, 0, stream>>>(x1, ln2_w, ln2_b, xnb);

    // MLP
    gemm_bf16_t<128><<<dim3(3072 / 128, Mrows / 128), blk, 0, stream>>>(
        xnb, wt_fc1, b_fc1, nullptr, midb, Mrows, 3072, Ch, 1 | 2, nullptr, nullptr);
    gemm_bf16_t<64><<<dim3(Ch / 64, Mrows / 128), blk, 0, stream>>>(
        midb, wt_fc2, b_fc2, x1, out, Mrows, Ch, 3072, 0, nullptr, nullptr);
}